// Round 19
// baseline (94.570 us; speedup 1.0000x reference)
//
#include <hip/hip_runtime.h>
#include <math.h>

#define NB 32
#define NL 2048
#define NH 8
#define NE 64
#define NM 64
#define MRI 128          // 2*NM (re stacked over im)
#define BK 128           // K per chunk
#define NCH 16           // 2048 / BK

typedef __attribute__((ext_vector_type(8))) __bf16 bf16x8;
typedef __attribute__((ext_vector_type(2))) __bf16 bf16x2;
typedef __attribute__((ext_vector_type(8))) unsigned short us8;
typedef __attribute__((ext_vector_type(4))) float f32x4;
typedef __attribute__((ext_vector_type(16))) float f32x16;

__device__ __forceinline__ unsigned short f2bf(float x) {
  unsigned int u = __builtin_bit_cast(unsigned int, x);
  u = (u + 0x7fffu + ((u >> 16) & 1u)) >> 16;
  return (unsigned short)u;
}
__device__ __forceinline__ float bf2f(unsigned short u) {
  return __builtin_bit_cast(float, (unsigned int)u << 16);
}
__device__ __forceinline__ unsigned int pk2(float lo, float hi) {
  bf16x2 v;
  v[0] = (__bf16)lo;
  v[1] = (__bf16)hi;
  return __builtin_bit_cast(unsigned int, v);
}

// ---------------- tables + W->bf16 (r18 verbatim, bit-exact verified) ----------------
// Tf: DFT twiddles in MFMA-FRAGMENT order: [c 16][kh 2][ks 4][tm 4][lane 64][j 8] bf16.
__global__ void tables_k(const int* __restrict__ idx,
                         const float* __restrict__ wr, const float* __restrict__ wi,
                         unsigned short* __restrict__ Tf, unsigned short* __restrict__ IT,
                         unsigned short* __restrict__ WBr, unsigned short* __restrict__ WBi) {
  int gid = blockIdx.x * blockDim.x + threadIdx.x;  // 0..262143
  const float w0 = 6.283185307179586f / (float)NL;
  {
    int j = gid & 7, lane_ = (gid >> 3) & 63, tm_ = (gid >> 9) & 3;
    int ks_ = (gid >> 11) & 3, kh_ = (gid >> 13) & 1, c_ = gid >> 14;
    int row = tm_ * 32 + (lane_ & 31);
    int m = row & 63;
    int k = c_ * 128 + kh_ * 64 + ks_ * 16 + (lane_ >> 5) * 8 + j;
    int f = idx[m];
    float s, c2;
    sincosf((float)((f * k) & (NL - 1)) * w0, &s, &c2);
    Tf[gid] = f2bf(row < 64 ? c2 : -s);
  }
  {
    int lp = gid >> 7, k = gid & 127;
    int m = k & 63;
    float s, c;
    sincosf((float)((m * lp) & (NL - 1)) * w0, &s, &c);
    float v = (k < 64) ? ((m == 0 ? 1.0f : 2.0f) / (float)NL) * c
                       : (m == 0 ? 0.0f : (-2.0f / (float)NL) * s);
    IT[gid] = f2bf(v);
  }
  {
    const float2* wr2 = (const float2*)wr;
    const float2* wi2 = (const float2*)wi;
    unsigned int* obr = (unsigned int*)WBr;
    unsigned int* obi = (unsigned int*)WBi;
#pragma unroll
    for (int r = 0; r < 4; ++r) {
      int j = r * 262144 + gid;
      float2 a = wr2[j];
      float2 b2 = wi2[j];
      obr[j] = pk2(a.x, a.y);
      obi[j] = pk2(b2.x, b2.y);
    }
  }
}

// ---------------- fused per-(b,h), 256 blocks x 512 thr, 2 blocks/CU ----------------
// 8 waves: wave (tm,te) owns one full-K 32x32 tile (128 MFMA) — no kh split.
// B (q): 3-buffer LDS rotation, ONE lgkm barrier per chunk (r18 skeleton).
// A (Tf): register ring from L2 fragment table; stalls covered by the co-resident block.
// LDS 53248 B total: B bufs 3x16896 @0; post-P1 Xs [128][272B] @0 ; OtB [64][256B] @36864.
__global__ __launch_bounds__(512, 4) void fused_k(const float* __restrict__ q,
                                                  const unsigned short* __restrict__ T,
                                                  const unsigned short* __restrict__ IT,
                                                  const unsigned short* __restrict__ WBr,
                                                  const unsigned short* __restrict__ WBi,
                                                  float* __restrict__ out) {
  __shared__ __align__(16) char smem[53248];
  int t = threadIdx.x, lane = t & 63, wid = t >> 6;
  int h = blockIdx.x & 7, b = blockIdx.x >> 3;

  // ================= P1: DFT  X = T * q  (32x32x16, full-K waves) =================
  {
    char* bC = smem;            // chunk c (being read)
    char* bN = smem + 16896;    // chunk c+1 (being written)
    char* bX = smem + 33792;    // free
    const float* qb = q + ((size_t)b * NL * NH + h) * NE;  // q[b][l][h][e]
    int tm = wid & 3;           // m-group of 32 rows
    int te = wid >> 2;          // e-group of 32 cols (0..1)
    int eq = t & 15, lq = t >> 4;   // staging: e-quad (coalesced), l-quad 0..31
    f32x16 acc32 = {};
    f32x4 qA[4], qB[4];
    us8 arA[8], arB[8];

    auto qload = [&](int c, f32x4* qr) {
#pragma unroll
      for (int p = 0; p < 4; ++p)
        qr[p] = *(const f32x4*)(qb + (size_t)(c * BK + lq * 4 + p) * (NH * NE) + eq * 4);
    };
    auto writesB = [&](const f32x4* qr, char* bb) {
#pragma unroll
      for (int j = 0; j < 4; ++j) {
        int e = eq * 4 + j;
        *(uint2*)(bb + e * 264 + lq * 8) =
            make_uint2(pk2(qr[0][j], qr[1][j]), pk2(qr[2][j], qr[3][j]));
      }
    };
    auto loadA = [&](int c, us8* ar) {
#pragma unroll
      for (int kf = 0; kf < 8; ++kf)
        ar[kf] = *(const us8*)(
            T + ((((size_t)c * 2 + (kf >> 2)) * 4 + (kf & 3)) * 4 + tm) * 512 + lane * 8);
    };
    auto compute = [&](const us8* ar, const char* bb) {
#pragma unroll
      for (int kf = 0; kf < 8; ++kf) {
        int e = te * 32 + (lane & 31);
        int boff = e * 264 + (kf * 16 + (lane >> 5) * 8) * 2;
        uint2 blo = *(const uint2*)(bb + boff);
        uint2 bhi = *(const uint2*)(bb + boff + 8);
        bf16x8 bfr = __builtin_bit_cast(bf16x8, make_uint4(blo.x, blo.y, bhi.x, bhi.y));
        acc32 = __builtin_amdgcn_mfma_f32_32x32x16_bf16(
            __builtin_bit_cast(bf16x8, ar[kf]), bfr, acc32, 0, 0, 0);
      }
    };
    auto rot = [&]() {
      char* tmp = bC;
      bC = bN;
      bN = bX;
      bX = tmp;
    };

    // prologue
    qload(0, qA);
    qload(1, qB);
    loadA(0, arA);
    writesB(qA, bC);
    asm volatile("s_waitcnt lgkmcnt(0)" ::: "memory");
    __builtin_amdgcn_s_barrier();
    // main loop: ONE lgkm-barrier per chunk (r18-verified rotation)
    for (int c = 0; c < NCH; c += 2) {
      loadA(c + 1, arB);
      if (c + 2 < NCH) qload(c + 2, qA);
      __builtin_amdgcn_sched_barrier(0);
      compute(arA, bC);
      writesB(qB, bN);
      asm volatile("s_waitcnt lgkmcnt(0)" ::: "memory");
      __builtin_amdgcn_s_barrier();
      rot();
      if (c + 2 < NCH) loadA(c + 2, arA);
      if (c + 3 < NCH) qload(c + 3, qB);
      __builtin_amdgcn_sched_barrier(0);
      compute(arB, bC);
      if (c + 2 < NCH) {
        writesB(qA, bN);
        asm volatile("s_waitcnt lgkmcnt(0)" ::: "memory");
        __builtin_amdgcn_s_barrier();
      }
      rot();
    }
    __syncthreads();

    // direct Xs write (no kh merge needed — each wave summed full K)
#pragma unroll
    for (int rg = 0; rg < 16; ++rg) {
      int row = (rg & 3) + 8 * (rg >> 2) + 4 * (lane >> 5);
      int grow = tm * 32 + row;          // m_ri
      int gcol = te * 32 + (lane & 31);  // e
      int off = (grow * 272 + gcol * 4) ^ (((grow >> 3) & 7) << 4);
      *(float*)(smem + off) = acc32[rg];
    }
  }
  __syncthreads();

  // ================= P2: mix (fp32 VALU, bf16 W from L2), 512 thr =================
  {
    char* OtB = smem + 36864;          // [64 o][128 m_ri] bf16, 256B rows, XOR (o&7)<<4
    int o = t >> 3, mq = t & 7;        // thread: 1 o, 8 m (m = mq*8+mi)
    const unsigned short* wbr = WBr + (size_t)h * 262144 + o * 64 + mq * 8;
    const unsigned short* wbi = WBi + (size_t)h * 262144 + o * 64 + mq * 8;
    float orr[8] = {}, oii[8] = {};
    for (int ib = 0; ib < 16; ++ib) {
      f32x4 xr4[8], xi4[8];
#pragma unroll
      for (int mi = 0; mi < 8; ++mi) {
        int m = mq * 8 + mi;
        xr4[mi] = *(const f32x4*)(smem + ((m * 272 + ib * 16) ^ (mq << 4)));
        xi4[mi] = *(const f32x4*)(smem + (((64 + m) * 272 + ib * 16) ^ (mq << 4)));
      }
      us8 wr8[4], wi8[4];
#pragma unroll
      for (int ii = 0; ii < 4; ++ii) {
        int i = ib * 4 + ii;
        wr8[ii] = *(const us8*)(wbr + (size_t)i * 4096);
        wi8[ii] = *(const us8*)(wbi + (size_t)i * 4096);
      }
#pragma unroll
      for (int ii = 0; ii < 4; ++ii)
#pragma unroll
        for (int mi = 0; mi < 8; ++mi) {
          float wrv = bf2f(wr8[ii][mi]);
          float wiv = bf2f(wi8[ii][mi]);
          orr[mi] += xr4[mi][ii] * wrv - xi4[mi][ii] * wiv;
          oii[mi] += xr4[mi][ii] * wiv + xi4[mi][ii] * wrv;
        }
    }
    __syncthreads();   // Xs fully consumed before OtB overlay region reuse ordering
    uint4 vr = make_uint4(pk2(orr[0], orr[1]), pk2(orr[2], orr[3]),
                          pk2(orr[4], orr[5]), pk2(orr[6], orr[7]));
    uint4 vi = make_uint4(pk2(oii[0], oii[1]), pk2(oii[2], oii[3]),
                          pk2(oii[4], oii[5]), pk2(oii[6], oii[7]));
    *(uint4*)(OtB + ((o * 256 + mq * 16) ^ ((o & 7) << 4))) = vr;
    *(uint4*)(OtB + ((o * 256 + 128 + mq * 16) ^ ((o & 7) << 4))) = vi;
  }
  __syncthreads();

  // ================= P3: iDFT  out = Ot * IT^T (nt stores), 512 thr =================
  {
    const char* OtB = smem + 36864;
    bf16x8 af[2][8];
#pragma unroll
    for (int rg2 = 0; rg2 < 2; ++rg2)
#pragma unroll
      for (int ks = 0; ks < 8; ++ks) {
        int row = rg2 * 32 + (lane & 31);
        int off = (row * 256 + ks * 32 + (lane >> 5) * 16) ^ ((row & 7) << 4);
        af[rg2][ks] = __builtin_bit_cast(bf16x8, *(const us8*)(OtB + off));
      }
    float* ob = out + ((size_t)(b * 8 + h) * 64) * NL;
    int l0 = wid * 256;
    for (int ct = 0; ct < 8; ++ct) {
      int lr = l0 + ct * 32 + (lane & 31);
      f32x16 a2[2] = {};
#pragma unroll
      for (int ks = 0; ks < 8; ++ks) {
        bf16x8 bv = __builtin_bit_cast(
            bf16x8, *(const us8*)(IT + (size_t)lr * MRI + ks * 16 + (lane >> 5) * 8));
        a2[0] = __builtin_amdgcn_mfma_f32_32x32x16_bf16(af[0][ks], bv, a2[0], 0, 0, 0);
        a2[1] = __builtin_amdgcn_mfma_f32_32x32x16_bf16(af[1][ks], bv, a2[1], 0, 0, 0);
      }
#pragma unroll
      for (int rg2 = 0; rg2 < 2; ++rg2)
#pragma unroll
        for (int rg = 0; rg < 16; ++rg) {
          int row = rg2 * 32 + ((rg & 3) + 8 * (rg >> 2) + 4 * (lane >> 5));
          __builtin_nontemporal_store(a2[rg2][rg], &ob[(size_t)row * NL + lr]);
        }
    }
  }
}

extern "C" void kernel_launch(void* const* d_in, const int* in_sizes, int n_in,
                              void* d_out, int out_size, void* d_ws, size_t ws_size,
                              hipStream_t stream) {
  const float* q = (const float*)d_in[0];
  const float* wr = (const float*)d_in[3];
  const float* wi = (const float*)d_in[4];
  const int* idx = (const int*)d_in[5];
  float* out = (float*)d_out;
  char* ws = (char*)d_ws;

  constexpr size_t TBYTES = (size_t)MRI * NL * 2;            // 512 KB per table
  constexpr size_t WBBYTES = (size_t)NH * NE * NE * NM * 2;  // 4 MB per comp
  constexpr size_t NEED = 2 * TBYTES + 2 * WBBYTES;
  if (ws_size < NEED) return;

  unsigned short* Tf = (unsigned short*)ws;
  unsigned short* IT = (unsigned short*)(ws + TBYTES);
  unsigned short* WBr = (unsigned short*)(ws + 2 * TBYTES);
  unsigned short* WBi = (unsigned short*)(ws + 2 * TBYTES + WBBYTES);

  hipLaunchKernelGGL(tables_k, dim3(1024), dim3(256), 0, stream, idx, wr, wi, Tf, IT, WBr, WBi);
  hipLaunchKernelGGL(fused_k, dim3(NB * NH), dim3(512), 0, stream, q, Tf, IT, WBr, WBi, out);
}

// Round 20
// 82.177 us; speedup vs baseline: 1.1508x; 1.1508x over previous
//
#include <hip/hip_runtime.h>
#include <math.h>

#define NB 32
#define NL 2048
#define NH 8
#define NE 64
#define NM 64
#define MRI 128          // 2*NM (re stacked over im)
#define BK 128           // K per chunk
#define NCH 16           // 2048 / BK

typedef __attribute__((ext_vector_type(8))) __bf16 bf16x8;
typedef __attribute__((ext_vector_type(2))) __bf16 bf16x2;
typedef __attribute__((ext_vector_type(8))) unsigned short us8;
typedef __attribute__((ext_vector_type(4))) unsigned short us4;
typedef __attribute__((ext_vector_type(4))) float f32x4;
typedef __attribute__((ext_vector_type(16))) float f32x16;

__device__ __forceinline__ unsigned short f2bf(float x) {
  unsigned int u = __builtin_bit_cast(unsigned int, x);
  u = (u + 0x7fffu + ((u >> 16) & 1u)) >> 16;
  return (unsigned short)u;
}
__device__ __forceinline__ float bf2f(unsigned short u) {
  return __builtin_bit_cast(float, (unsigned int)u << 16);
}
__device__ __forceinline__ unsigned int pk2(float lo, float hi) {
  bf16x2 v;
  v[0] = (__bf16)lo;
  v[1] = (__bf16)hi;
  return __builtin_bit_cast(unsigned int, v);
}

// ---------------- tables + W->bf16 ----------------
// Tf : DFT twiddles in MFMA-fragment order [c 16][kh 2][ks 4][tm 4][lane 64][j 8] (r13, bit-exact).
// ITf: iDFT twiddles in MFMA-fragment order [lrblk 64][ks 8][lane 64][j 8]:
//      row l' = lrblk*32 + (lane&31); elem m_ri = ks*16 + (lane>>5)*8 + j;
//      val = (m_ri<64 ? s_m*cos : -s_m*sin)(2pi*(m_ri&63)*l'/L), s_m = (m?2:1)/L.
// WB r/i: w_real/imag [h][i][o][m] -> bf16 (W[h] bf16 = 4 MB -> L2-resident/XCD)
__global__ void tables_k(const int* __restrict__ idx,
                         const float* __restrict__ wr, const float* __restrict__ wi,
                         unsigned short* __restrict__ Tf, unsigned short* __restrict__ ITf,
                         unsigned short* __restrict__ WBr, unsigned short* __restrict__ WBi) {
  int gid = blockIdx.x * blockDim.x + threadIdx.x;  // 0..262143
  const float w0 = 6.283185307179586f / (float)NL;
  {
    int j = gid & 7, lane_ = (gid >> 3) & 63, tm_ = (gid >> 9) & 3;
    int ks_ = (gid >> 11) & 3, kh_ = (gid >> 13) & 1, c_ = gid >> 14;
    int row = tm_ * 32 + (lane_ & 31);
    int m = row & 63;
    int k = c_ * 128 + kh_ * 64 + ks_ * 16 + (lane_ >> 5) * 8 + j;
    int f = idx[m];
    float s, c2;
    sincosf((float)((f * k) & (NL - 1)) * w0, &s, &c2);
    Tf[gid] = f2bf(row < 64 ? c2 : -s);
  }
  {
    int j = gid & 7, lane_ = (gid >> 3) & 63, ks_ = (gid >> 9) & 7, lrb = gid >> 12;
    int lp = lrb * 32 + (lane_ & 31);
    int kmri = ks_ * 16 + (lane_ >> 5) * 8 + j;
    int m = kmri & 63;
    float s, c;
    sincosf((float)((m * lp) & (NL - 1)) * w0, &s, &c);
    float v = (kmri < 64) ? ((m == 0 ? 1.0f : 2.0f) / (float)NL) * c
                          : (m == 0 ? 0.0f : (-2.0f / (float)NL) * s);
    ITf[gid] = f2bf(v);
  }
  {
    const float2* wr2 = (const float2*)wr;
    const float2* wi2 = (const float2*)wi;
    unsigned int* obr = (unsigned int*)WBr;
    unsigned int* obi = (unsigned int*)WBi;
#pragma unroll
    for (int r = 0; r < 4; ++r) {
      int j = r * 262144 + gid;
      float2 a = wr2[j];
      float2 b2 = wi2[j];
      obr[j] = pk2(a.x, a.y);
      obi[j] = pk2(b2.x, b2.y);
    }
  }
}

// ---------------- fused per-(b,h), 256 blocks x 1024 thr (r18 base) ----------------
// P1: A in register ring (Tf fragment table); B (q) 3-buffer LDS rotation,
//     ONE lgkm-only barrier per chunk. P3: BOTH operands fragment-order coalesced.
// LDS: Xs [128][272B] @0 ; B bufs 3x16896 @34816 ; scr 32KB @34816 (post-P1);
//      OtB [64][256B] @67584.  Total 85504 B.
__global__ __launch_bounds__(1024) void fused_k(const float* __restrict__ q,
                                                const unsigned short* __restrict__ T,
                                                const unsigned short* __restrict__ ITf,
                                                const unsigned short* __restrict__ WBr,
                                                const unsigned short* __restrict__ WBi,
                                                float* __restrict__ out) {
  __shared__ __align__(16) char smem[85504];
  int t = threadIdx.x, lane = t & 63, wid = t >> 6;
  int h = blockIdx.x & 7, b = blockIdx.x >> 3;

  // ================= P1: DFT  X = T * q  (32x32x16, K-half wave split) =================
  {
    char* bC = smem + 34816;            // chunk c (being read)
    char* bN = smem + 34816 + 16896;    // chunk c+1 (being written)
    char* bX = smem + 34816 + 33792;    // chunk c+2 (free)
    const float* qb = q + ((size_t)b * NL * NH + h) * NE;  // q[b][l][h][e]
    int tm = wid & 3;           // m-group of 32 rows
    int te = (wid >> 2) & 1;    // e-group of 32 cols
    int kh = wid >> 3;          // K-half within chunk
    int eq = t & 15, lq = t >> 4;   // staging: e-quad (coalesced), l-pair
    f32x16 acc32 = {};
    f32x4 qA[2], qB[2];
    us8 arA[4], arB[4];

    auto qload = [&](int c, f32x4* qr) {
#pragma unroll
      for (int p = 0; p < 2; ++p)
        qr[p] = *(const f32x4*)(qb + (size_t)(c * BK + lq * 2 + p) * (NH * NE) + eq * 4);
    };
    auto writesB = [&](const f32x4* qr, char* bb) {
#pragma unroll
      for (int j = 0; j < 4; ++j) {
        int e = eq * 4 + j;
        *(unsigned int*)(bb + e * 264 + lq * 4) = pk2(qr[0][j], qr[1][j]);
      }
    };
    auto loadA = [&](int c, us8* ar) {
#pragma unroll
      for (int ks = 0; ks < 4; ++ks)
        ar[ks] = *(const us8*)(T + ((((size_t)c * 2 + kh) * 4 + ks) * 4 + tm) * 512 + lane * 8);
    };
    auto compute = [&](const us8* ar, const char* bb) {
#pragma unroll
      for (int ks = 0; ks < 4; ++ks) {
        int k0 = (kh * 4 + ks) * 16;
        int e = te * 32 + (lane & 31);
        int boff = e * 264 + (k0 + (lane >> 5) * 8) * 2;
        uint2 blo = *(const uint2*)(bb + boff);
        uint2 bhi = *(const uint2*)(bb + boff + 8);
        bf16x8 bfr = __builtin_bit_cast(bf16x8, make_uint4(blo.x, blo.y, bhi.x, bhi.y));
        acc32 = __builtin_amdgcn_mfma_f32_32x32x16_bf16(
            __builtin_bit_cast(bf16x8, ar[ks]), bfr, acc32, 0, 0, 0);
      }
    };
    auto rot = [&]() {
      char* tmp = bC;
      bC = bN;
      bN = bX;
      bX = tmp;
    };

    // prologue
    qload(0, qA);
    qload(1, qB);
    loadA(0, arA);
    writesB(qA, bC);   // per-wave auto vmcnt on qA; qB/arA stay in flight
    asm volatile("s_waitcnt lgkmcnt(0)" ::: "memory");
    __builtin_amdgcn_s_barrier();
    // main loop: ONE lgkm-barrier per chunk; prefetches pinned above compute
    for (int c = 0; c < NCH; c += 2) {
      loadA(c + 1, arB);
      if (c + 2 < NCH) qload(c + 2, qA);
      __builtin_amdgcn_sched_barrier(0);     // pin prefetch issue above compute
      compute(arA, bC);
      writesB(qB, bN);                       // q(c+1), loaded one chunk ago
      asm volatile("s_waitcnt lgkmcnt(0)" ::: "memory");
      __builtin_amdgcn_s_barrier();
      rot();
      if (c + 2 < NCH) loadA(c + 2, arA);
      if (c + 3 < NCH) qload(c + 3, qB);
      __builtin_amdgcn_sched_barrier(0);
      compute(arB, bC);
      if (c + 2 < NCH) {
        writesB(qA, bN);
        asm volatile("s_waitcnt lgkmcnt(0)" ::: "memory");
        __builtin_amdgcn_s_barrier();
      }
      rot();
    }
    __syncthreads();

    // K-half merge via scratch (over dead B bufs), then Xs write
    float* scr = (float*)(smem + 34816);  // 8 tiles x 32x32 f32 = 32 KB
    int tile = wid & 7;
    if (kh == 1) {
#pragma unroll
      for (int r = 0; r < 16; ++r) {
        int row = (r & 3) + 8 * (r >> 2) + 4 * (lane >> 5);
        scr[tile * 1024 + row * 32 + (lane & 31)] = acc32[r];
      }
    }
    __syncthreads();
    if (kh == 0) {
#pragma unroll
      for (int r = 0; r < 16; ++r) {
        int row = (r & 3) + 8 * (r >> 2) + 4 * (lane >> 5);
        float v = acc32[r] + scr[tile * 1024 + row * 32 + (lane & 31)];
        int grow = tm * 32 + row;          // m_ri
        int gcol = te * 32 + (lane & 31);  // e
        int off = (grow * 272 + gcol * 4) ^ (((grow >> 3) & 7) << 4);
        *(float*)(smem + off) = v;
      }
    }
  }
  __syncthreads();

  // ================= P2: mix (fp32 VALU, bf16 W from L2) =================
  {
    char* OtB = smem + 67584;          // [64 o][128 m_ri] bf16, 256B rows, XOR (o&7)<<4
    int o = t >> 4, mq = t & 15;       // thread: 1 o, 4 m (m = mq*4+mi)
    const unsigned short* wbr = WBr + (size_t)h * 262144 + o * 64 + mq * 4;
    const unsigned short* wbi = WBi + (size_t)h * 262144 + o * 64 + mq * 4;
    float orr[4] = {}, oii[4] = {};
#pragma unroll 2
    for (int ib = 0; ib < 16; ++ib) {
      f32x4 xr4[4], xi4[4];
#pragma unroll
      for (int mi = 0; mi < 4; ++mi) {
        int m = mq * 4 + mi;
        xr4[mi] = *(const f32x4*)(smem + ((m * 272 + ib * 16) ^ (((m >> 3) & 7) << 4)));
        xi4[mi] = *(const f32x4*)(smem + (((64 + m) * 272 + ib * 16) ^ (((m >> 3) & 7) << 4)));
      }
      us4 wr4[4], wi4[4];
#pragma unroll
      for (int ii = 0; ii < 4; ++ii) {
        int i = ib * 4 + ii;
        wr4[ii] = *(const us4*)(wbr + (size_t)i * 4096);
        wi4[ii] = *(const us4*)(wbi + (size_t)i * 4096);
      }
#pragma unroll
      for (int ii = 0; ii < 4; ++ii)
#pragma unroll
        for (int mi = 0; mi < 4; ++mi) {
          float wrv = bf2f(wr4[ii][mi]);
          float wiv = bf2f(wi4[ii][mi]);
          orr[mi] += xr4[mi][ii] * wrv - xi4[mi][ii] * wiv;
          oii[mi] += xr4[mi][ii] * wiv + xi4[mi][ii] * wrv;
        }
    }
    uint2 vr = make_uint2(pk2(orr[0], orr[1]), pk2(orr[2], orr[3]));
    uint2 vi = make_uint2(pk2(oii[0], oii[1]), pk2(oii[2], oii[3]));
    *(uint2*)(OtB + ((o * 256 + mq * 8) ^ ((o & 7) << 4))) = vr;
    *(uint2*)(OtB + ((o * 256 + 128 + mq * 8) ^ ((o & 7) << 4))) = vi;
  }
  __syncthreads();

  // ================= P3: iDFT  out = Ot * ITf (coalesced fragment B, nt stores) =================
  {
    const char* OtB = smem + 67584;
    bf16x8 af[2][8];
#pragma unroll
    for (int rg2 = 0; rg2 < 2; ++rg2)
#pragma unroll
      for (int ks = 0; ks < 8; ++ks) {
        int row = rg2 * 32 + (lane & 31);
        int off = (row * 256 + ks * 32 + (lane >> 5) * 16) ^ ((row & 7) << 4);
        af[rg2][ks] = __builtin_bit_cast(bf16x8, *(const us8*)(OtB + off));
      }
    float* ob = out + ((size_t)(b * 8 + h) * 64) * NL;
    int l0 = wid * 128;
    for (int ct = 0; ct < 4; ++ct) {
      int lr = l0 + ct * 32 + (lane & 31);
      int lrb = wid * 4 + ct;            // lr >> 5
      f32x16 a2[2] = {};
#pragma unroll
      for (int ks = 0; ks < 8; ++ks) {
        bf16x8 bv = __builtin_bit_cast(
            bf16x8, *(const us8*)(ITf + (((size_t)lrb * 8 + ks) * 64 + lane) * 8));
        a2[0] = __builtin_amdgcn_mfma_f32_32x32x16_bf16(af[0][ks], bv, a2[0], 0, 0, 0);
        a2[1] = __builtin_amdgcn_mfma_f32_32x32x16_bf16(af[1][ks], bv, a2[1], 0, 0, 0);
      }
#pragma unroll
      for (int rg2 = 0; rg2 < 2; ++rg2)
#pragma unroll
        for (int rg = 0; rg < 16; ++rg) {
          int row = rg2 * 32 + ((rg & 3) + 8 * (rg >> 2) + 4 * (lane >> 5));
          __builtin_nontemporal_store(a2[rg2][rg], &ob[(size_t)row * NL + lr]);
        }
    }
  }
}

extern "C" void kernel_launch(void* const* d_in, const int* in_sizes, int n_in,
                              void* d_out, int out_size, void* d_ws, size_t ws_size,
                              hipStream_t stream) {
  const float* q = (const float*)d_in[0];
  const float* wr = (const float*)d_in[3];
  const float* wi = (const float*)d_in[4];
  const int* idx = (const int*)d_in[5];
  float* out = (float*)d_out;
  char* ws = (char*)d_ws;

  constexpr size_t TBYTES = (size_t)MRI * NL * 2;            // 512 KB per table
  constexpr size_t WBBYTES = (size_t)NH * NE * NE * NM * 2;  // 4 MB per comp
  constexpr size_t NEED = 2 * TBYTES + 2 * WBBYTES;
  if (ws_size < NEED) return;

  unsigned short* Tf = (unsigned short*)ws;
  unsigned short* ITf = (unsigned short*)(ws + TBYTES);
  unsigned short* WBr = (unsigned short*)(ws + 2 * TBYTES);
  unsigned short* WBi = (unsigned short*)(ws + 2 * TBYTES + WBBYTES);

  hipLaunchKernelGGL(tables_k, dim3(1024), dim3(256), 0, stream, idx, wr, wi, Tf, ITf, WBr, WBi);
  hipLaunchKernelGGL(fused_k, dim3(NB * NH), dim3(1024), 0, stream, q, Tf, ITf, WBr, WBi, out);
}